// Round 6
// baseline (855.496 us; speedup 1.0000x reference)
//
#include <hip/hip_runtime.h>

typedef unsigned int   uint32;
typedef unsigned short ushort16;

#define NN       50000
#define RR       16
#define BB       8
#define DIN      128
#define DOUT     128
#define KK       2048          // R*DIN
#define NNZ_C    1600000
#define NBUCK    196           // row>>8 buckets (256 rows each)
#define EPB      4096          // edges per block in sort passes
#define NBLK_E   391           // ceil(NNZ/EPB)
#define MROWS    32            // rows per fused block
#define NBLK_F   1563          // ceil(NN/MROWS)

typedef short  short8  __attribute__((ext_vector_type(8)));
typedef float  floatx4 __attribute__((ext_vector_type(4)));

__device__ __forceinline__ ushort16 f2bf(float f) {
    uint32 u = __float_as_uint(f);
    u += 0x7fffu + ((u >> 16) & 1u);   // RNE
    return (ushort16)(u >> 16);
}

__device__ __forceinline__ float bf2f(ushort16 h) {
    return __uint_as_float(((uint32)h) << 16);
}

// pack two f32 -> (bf16(b)<<16)|bf16(a), round-half-up
__device__ __forceinline__ uint32 pack_bf16(float a, float b) {
    uint32 ua = __float_as_uint(a) + 0x8000u;
    uint32 ub = __float_as_uint(b) + 0x8000u;
    return __builtin_amdgcn_perm(ub, ua, 0x07060302);
}

// ---------------------------------------------------------------------------
// Wst[jout][r*128+jin] = sum_b comp[r][b] * basis[b][jin][jout]  (bf16)
// ---------------------------------------------------------------------------
__global__ void build_wst_kernel(const float* __restrict__ basis,
                                 const float* __restrict__ comp,
                                 ushort16* __restrict__ Wst) {
    int idx  = blockIdx.x * 256 + threadIdx.x;   // 128*2048 = 262144
    int jout = idx >> 11;
    int rk   = idx & 2047;
    int r    = rk >> 7;
    int jin  = rk & 127;
    float s = 0.f;
#pragma unroll
    for (int b = 0; b < BB; ++b)
        s += comp[r * BB + b] * basis[((size_t)b * DIN + jin) * DOUT + jout];
    Wst[idx] = f2bf(s);
}

// ---------------------------------------------------------------------------
// X (f32, N x 128) -> XD (bf16 packed dwords, N x 64 dwords)
// ---------------------------------------------------------------------------
__global__ void cvt_x_kernel(const float* __restrict__ X,
                             uint32* __restrict__ XD) {
    int d = blockIdx.x * 256 + threadIdx.x;      // 3,200,000 dwords
    float2 f = *(const float2*)(X + (size_t)d * 2);
    XD[d] = pack_bf16(f.x, f.y);
}

// ---------------------------------------------------------------------------
// Sort pass 1: global bucket histogram (LDS-aggregated)
// ---------------------------------------------------------------------------
__global__ void histB_kernel(const int* __restrict__ rows,
                             int* __restrict__ counts) {
    __shared__ int h[NBUCK];
    int tid = threadIdx.x;
    if (tid < NBUCK) h[tid] = 0;
    __syncthreads();
    int base_e = blockIdx.x * EPB;
#pragma unroll
    for (int it = 0; it < 16; ++it) {
        int e = base_e + it * 256 + tid;
        if (e < NNZ_C) atomicAdd(&h[rows[e] >> 8], 1);
    }
    __syncthreads();
    if (tid < NBUCK && h[tid]) atomicAdd(&counts[tid], h[tid]);
}

// ---------------------------------------------------------------------------
// Sort pass 2: scan 196 bucket counts; init cursors
// ---------------------------------------------------------------------------
__global__ void scanB_kernel(const int* __restrict__ counts,
                             int* __restrict__ bucket_start,
                             int* __restrict__ cursor) {
    __shared__ int tmp[256];
    int tid = threadIdx.x;
    int v = (tid < NBUCK) ? counts[tid] : 0;
    tmp[tid] = v;
    __syncthreads();
#pragma unroll
    for (int off = 1; off < 256; off <<= 1) {
        int t = (tid >= off) ? tmp[tid - off] : 0;
        __syncthreads();
        tmp[tid] += t;
        __syncthreads();
    }
    if (tid < NBUCK) {
        bucket_start[tid + 1] = tmp[tid];          // inclusive
        cursor[tid] = tmp[tid] - v;                // exclusive
        if (tid == 0) bucket_start[0] = 0;
    }
}

// ---------------------------------------------------------------------------
// Sort pass 3: per-block range reservation + scatter into bucket-grouped es2
// payload x = c(16b) | kl(12b)<<16, kl = (row&255)*16 + r ; y = val bits
// ---------------------------------------------------------------------------
__global__ __launch_bounds__(256) void scatterB_kernel(
        const int* __restrict__ rows,
        const int* __restrict__ cols,
        const float* __restrict__ vals,
        int* __restrict__ cursor,
        uint2* __restrict__ es2) {
    __shared__ int h[NBUCK], gbase[NBUCK], lcur[NBUCK];
    int tid = threadIdx.x;
    if (tid < NBUCK) { h[tid] = 0; lcur[tid] = 0; }
    __syncthreads();

    int    rowv[16];
    uint32 pkx[16];
    float  vv[16];
    int base_e = blockIdx.x * EPB;
#pragma unroll
    for (int it = 0; it < 16; ++it) {
        int e = base_e + it * 256 + tid;
        if (e < NNZ_C) {
            int row = rows[e];
            int col = cols[e];
            int r   = (int)((uint32)col / (uint32)NN);
            int c   = col - r * NN;
            rowv[it] = row;
            pkx[it]  = (uint32)c | ((uint32)(((row & 255) << 4) | r) << 16);
            vv[it]   = vals[e];
            atomicAdd(&h[row >> 8], 1);
        } else rowv[it] = -1;
    }
    __syncthreads();
    if (tid < NBUCK && h[tid] > 0)
        gbase[tid] = atomicAdd(&cursor[tid], h[tid]);
    __syncthreads();
#pragma unroll
    for (int it = 0; it < 16; ++it) {
        if (rowv[it] >= 0) {
            int b   = rowv[it] >> 8;
            int pos = gbase[b] + atomicAdd(&lcur[b], 1);
            es2[pos] = make_uint2(pkx[it], __float_as_uint(vv[it]));
        }
    }
}

// ---------------------------------------------------------------------------
// Sort pass 4: one block per bucket — LDS counting-sort by sub-key
// kl = (row&255)*16 + r ; writes final es (x = c, y = val) and
// ks[b*4096 + kl] == ks[row*16 + r] = global segment start.
// ---------------------------------------------------------------------------
__global__ __launch_bounds__(256) void sortB_kernel(
        const uint2* __restrict__ es2,
        const int* __restrict__ bucket_start,
        uint2* __restrict__ es,
        int* __restrict__ ks) {
    __shared__ int h[4096];
    __shared__ int cur[4096];
    __shared__ int tmp[256];
    int b    = blockIdx.x;
    int tid  = threadIdx.x;
    int base = bucket_start[b];
    int n    = bucket_start[b + 1] - base;

#pragma unroll
    for (int j = 0; j < 16; ++j) h[j * 256 + tid] = 0;
    __syncthreads();
    for (int i = tid; i < n; i += 256) {
        uint2 p = es2[base + i];
        atomicAdd(&h[(p.x >> 16) & 0xfffu], 1);
    }
    __syncthreads();

    int run = 0;
    int loc[16];
#pragma unroll
    for (int j = 0; j < 16; ++j) {
        int c = h[tid * 16 + j];
        loc[j] = run;
        run += c;
    }
    tmp[tid] = run;
    __syncthreads();
#pragma unroll
    for (int off = 1; off < 256; off <<= 1) {
        int t = (tid >= off) ? tmp[tid - off] : 0;
        __syncthreads();
        tmp[tid] += t;
        __syncthreads();
    }
    int excl_t = tmp[tid] - run;
#pragma unroll
    for (int j = 0; j < 16; ++j) {
        int idx = tid * 16 + j;
        int st  = loc[j] + excl_t;
        cur[idx] = st;
        ks[b * 4096 + idx] = base + st;
    }
    __syncthreads();

    for (int i = tid; i < n; i += 256) {
        uint2 p  = es2[base + i];
        int   kl = (p.x >> 16) & 0xfffu;
        int  pos = atomicAdd(&cur[kl], 1);
        es[base + pos] = make_uint2(p.x & 0xffffu, p.y);
    }
}

// ---------------------------------------------------------------------------
// Fused Y-build + GEMM. One block = 32 output rows, 512 threads (8 waves).
// Build: wave w walks rows w*4..w*4+3 (4 interleaved streams, register
// accumulation per (row,r) segment, plain ds_write flush — no LDS atomics,
// ONE barrier). Y tile: 32 x 2048 bf16 = 128 KB LDS, 16B-chunk XOR swizzle.
// GEMM: wave w owns jout tile w*16..+16; B-frags streamed from L2-resident
// Wst (one 64B line per jout per slab); A-frags ds_read_b128 from Y.
// ---------------------------------------------------------------------------
#define YSWZ(row, dw) ((dw) ^ (((row) & 7) << 2))

__global__ __launch_bounds__(512) void yg_fused_kernel(
        const uint2* __restrict__ es,
        const int* __restrict__ ks,
        const uint32* __restrict__ XD,
        const ushort16* __restrict__ Wst,
        float* __restrict__ out) {
    __shared__ uint32 YL[MROWS * 1024];     // 131072 B

    const int tid  = threadIdx.x;
    const int wave = tid >> 6;              // 0..7
    const int lane = tid & 63;
    const int blk  = blockIdx.x;

    // ---------------- build phase ----------------
    {
        const int rl_base = wave * 4;                 // local row base
        int   e[4], endv[4], rcur[4], nxt[4], sreg[4];
        float a0[4], a1[4];
        uint2  pcur[4];
        uint32 xcur[4];
        bool   valid[4];

#pragma unroll
        for (int s = 0; s < 4; ++s) {
            int row = blk * MROWS + rl_base + s;
            valid[s] = (row < NN);
            int kv = 0;
            if (valid[s] && lane < 17) kv = ks[row * 16 + lane];
            sreg[s] = kv;
            e[s]    = valid[s] ? __shfl(kv, 0)  : 0;
            endv[s] = valid[s] ? __shfl(kv, 16) : 0;
            rcur[s] = 0;
            nxt[s]  = valid[s] ? __shfl(kv, 1) : 0x7fffffff;
            a0[s] = a1[s] = 0.f;
            if (e[s] < endv[s]) pcur[s] = es[e[s]];
        }
#pragma unroll
        for (int s = 0; s < 4; ++s)
            if (e[s] < endv[s])
                xcur[s] = XD[(size_t)pcur[s].x * 64 + lane];

#define FLUSH(s)                                                          \
        { int rl_ = rl_base + (s);                                        \
          YL[rl_ * 1024 + YSWZ(rl_, rcur[s] * 64 + lane)] =               \
              pack_bf16(a0[s], a1[s]);                                    \
          a0[s] = a1[s] = 0.f; rcur[s]++;                                 \
          nxt[s] = (rcur[s] < 16) ? __shfl(sreg[s], rcur[s] + 1)          \
                                  : 0x7fffffff; }

        for (;;) {
            bool progressed = false;
#pragma unroll
            for (int s = 0; s < 4; ++s) {
                if (e[s] >= endv[s]) continue;
                progressed = true;
                int   en = e[s] + 1;
                uint2 pn = make_uint2(0u, 0u);
                bool  hn = (en < endv[s]);
                if (hn) pn = es[en];                       // prefetch es
                while (e[s] >= nxt[s] && rcur[s] < 16) FLUSH(s)
                float v = __uint_as_float(pcur[s].y);
                a0[s] += v * bf2f((ushort16)(xcur[s] & 0xffffu));
                a1[s] += v * bf2f((ushort16)(xcur[s] >> 16));
                e[s] = en;
                pcur[s] = pn;
                if (hn) xcur[s] = XD[(size_t)pn.x * 64 + lane];
            }
            if (!progressed) break;
        }
#pragma unroll
        for (int s = 0; s < 4; ++s) {
            if (!valid[s]) continue;
            while (rcur[s] < 16) FLUSH(s)
        }
#undef FLUSH
    }
    __syncthreads();

    // ---------------- GEMM phase ----------------
    {
        const int m    = lane & 15;
        const int half = lane >> 4;
        const int sw   = (m & 7) << 2;
        const ushort16* wrow = Wst + (size_t)(wave * 16 + m) * KK;
        const uint32*   ya0  = &YL[m * 1024];
        const uint32*   ya1  = &YL[(m + 16) * 1024];

        floatx4 acc0 = {}, acc1 = {};
#pragma unroll 8
        for (int sl = 0; sl < 64; ++sl) {
            short8 bf  = *(const short8*)(wrow + sl * 32 + half * 8);
            int    adw = (sl * 16 + half * 4) ^ sw;
            short8 af0 = *(const short8*)(ya0 + adw);
            short8 af1 = *(const short8*)(ya1 + adw);
            acc0 = __builtin_amdgcn_mfma_f32_16x16x32_bf16(af0, bf, acc0, 0, 0, 0);
            acc1 = __builtin_amdgcn_mfma_f32_16x16x32_bf16(af1, bf, acc1, 0, 0, 0);
        }

        // C/D layout: col = m (jout = wave*16+m), tile-row = half*4+reg
#pragma unroll
        for (int reg = 0; reg < 4; ++reg) {
            int gr0 = blk * MROWS + half * 4 + reg;
            int gr1 = gr0 + 16;
            if (gr0 < NN) out[(size_t)gr0 * DOUT + wave * 16 + m] = acc0[reg];
            if (gr1 < NN) out[(size_t)gr1 * DOUT + wave * 16 + m] = acc1[reg];
        }
    }
}

// ---------------------------------------------------------------------------
extern "C" void kernel_launch(void* const* d_in, const int* in_sizes, int n_in,
                              void* d_out, int out_size, void* d_ws, size_t ws_size,
                              hipStream_t stream) {
    const float* X      = (const float*)d_in[0];
    const int*   A_rows = (const int*)d_in[1];
    const int*   A_cols = (const int*)d_in[2];
    const float* A_vals = (const float*)d_in[3];
    const float* basis  = (const float*)d_in[4];
    const float* comp   = (const float*)d_in[5];
    float* out = (float*)d_out;

    // workspace layout (~42.5 MB total)
    char* ws = (char*)d_ws;
    ushort16* Wst          = (ushort16*)(ws + 0);            // 512 KB
    uint32*   XD           = (uint32*)(ws + 524288);         // 12.8 MB
    int*      ks           = (int*)(ws + 13324288);          // 802816 ints
    uint2*    es           = (uint2*)(ws + 16535552);        // 12.8 MB
    int*      bucket_start = (int*)(ws + 29335552);          // 197 ints
    int*      counts       = (int*)(ws + 29336576);          // 196 ints
    int*      cursor       = (int*)(ws + 29337600);          // 196 ints
    uint2*    es2          = (uint2*)(ws + 29339648);        // 12.8 MB

    hipMemsetAsync(counts, 0, NBUCK * sizeof(int), stream);

    build_wst_kernel<<<1024, 256, 0, stream>>>(basis, comp, Wst);
    cvt_x_kernel<<<12500, 256, 0, stream>>>(X, XD);

    histB_kernel<<<NBLK_E, 256, 0, stream>>>(A_rows, counts);
    scanB_kernel<<<1, 256, 0, stream>>>(counts, bucket_start, cursor);
    scatterB_kernel<<<NBLK_E, 256, 0, stream>>>(A_rows, A_cols, A_vals,
                                                cursor, es2);
    sortB_kernel<<<NBUCK, 256, 0, stream>>>(es2, bucket_start, es, ks);

    yg_fused_kernel<<<NBLK_F, 512, 0, stream>>>(es, ks, XD, Wst, out);
}

// Round 7
// 548.290 us; speedup vs baseline: 1.5603x; 1.5603x over previous
//
#include <hip/hip_runtime.h>

typedef unsigned int   uint32;
typedef unsigned short ushort16;

#define NN       50000
#define RR       16
#define BB       8
#define DIN      128
#define DOUT     128
#define KK       2048          // R*DIN
#define NNZ_C    1600000
#define NBUCK    196           // row>>8 buckets (256 rows each)
#define EPB      4096          // edges per block in sort passes
#define NBLK_E   391           // ceil(NNZ/EPB)
#define ROWSPLIT 25024         // phase boundary (multiple of 64)

typedef short  short8  __attribute__((ext_vector_type(8)));
typedef float  floatx4 __attribute__((ext_vector_type(4)));

__device__ __forceinline__ ushort16 f2bf(float f) {
    uint32 u = __float_as_uint(f);
    u += 0x7fffu + ((u >> 16) & 1u);   // RNE
    return (ushort16)(u >> 16);
}

__device__ __forceinline__ float bf2f(ushort16 h) {
    return __uint_as_float(((uint32)h) << 16);
}

// pack two f32 -> (bf16(b)<<16)|bf16(a), round-half-up
__device__ __forceinline__ uint32 pack_bf16(float a, float b) {
    uint32 ua = __float_as_uint(a) + 0x8000u;
    uint32 ub = __float_as_uint(b) + 0x8000u;
    return __builtin_amdgcn_perm(ub, ua, 0x07060302);
}

// ---------------------------------------------------------------------------
// Wst[jout][r*128+jin] = sum_b comp[r][b] * basis[b][jin][jout]  (bf16,
// rk-contiguous so GEMM B-fragments are contiguous loads)
// ---------------------------------------------------------------------------
__global__ void build_wst_kernel(const float* __restrict__ basis,
                                 const float* __restrict__ comp,
                                 ushort16* __restrict__ Wst) {
    int idx  = blockIdx.x * 256 + threadIdx.x;   // 128*2048 = 262144
    int jout = idx >> 11;
    int rk   = idx & 2047;
    int r    = rk >> 7;
    int jin  = rk & 127;
    float s = 0.f;
#pragma unroll
    for (int b = 0; b < BB; ++b)
        s += comp[r * BB + b] * basis[((size_t)b * DIN + jin) * DOUT + jout];
    Wst[idx] = f2bf(s);
}

// ---------------------------------------------------------------------------
// X (f32, N x 128) -> XD (bf16 packed dwords, N x 64 dwords)
// ---------------------------------------------------------------------------
__global__ void cvt_x_kernel(const float* __restrict__ X,
                             uint32* __restrict__ XD) {
    int d = blockIdx.x * 256 + threadIdx.x;      // 3,200,000 dwords
    float2 f = *(const float2*)(X + (size_t)d * 2);
    XD[d] = pack_bf16(f.x, f.y);
}

// ---------------------------------------------------------------------------
// Sort pass 1: global bucket histogram (LDS-aggregated)
// ---------------------------------------------------------------------------
__global__ void histB_kernel(const int* __restrict__ rows,
                             int* __restrict__ counts) {
    __shared__ int h[NBUCK];
    int tid = threadIdx.x;
    if (tid < NBUCK) h[tid] = 0;
    __syncthreads();
    int base_e = blockIdx.x * EPB;
#pragma unroll
    for (int it = 0; it < 16; ++it) {
        int e = base_e + it * 256 + tid;
        if (e < NNZ_C) atomicAdd(&h[rows[e] >> 8], 1);
    }
    __syncthreads();
    if (tid < NBUCK && h[tid]) atomicAdd(&counts[tid], h[tid]);
}

// ---------------------------------------------------------------------------
// Sort pass 2: scan 196 bucket counts (single block); init cursors
// ---------------------------------------------------------------------------
__global__ void scanB_kernel(const int* __restrict__ counts,
                             int* __restrict__ bucket_start,
                             int* __restrict__ cursor) {
    __shared__ int tmp[256];
    int tid = threadIdx.x;
    int v = (tid < NBUCK) ? counts[tid] : 0;
    tmp[tid] = v;
    __syncthreads();
#pragma unroll
    for (int off = 1; off < 256; off <<= 1) {
        int t = (tid >= off) ? tmp[tid - off] : 0;
        __syncthreads();
        tmp[tid] += t;
        __syncthreads();
    }
    if (tid < NBUCK) {
        bucket_start[tid + 1] = tmp[tid];          // inclusive
        cursor[tid] = tmp[tid] - v;                // exclusive
        if (tid == 0) bucket_start[0] = 0;
    }
}

// ---------------------------------------------------------------------------
// Sort pass 3: per-block range reservation + scatter into bucket-grouped es2.
// payload x = c(16b) | kl(12b)<<16, kl = (row&255)*16 + r ; y = val bits
// ---------------------------------------------------------------------------
__global__ __launch_bounds__(256) void scatterB_kernel(
        const int* __restrict__ rows,
        const int* __restrict__ cols,
        const float* __restrict__ vals,
        int* __restrict__ cursor,
        uint2* __restrict__ es2) {
    __shared__ int h[NBUCK], gbase[NBUCK], lcur[NBUCK];
    int tid = threadIdx.x;
    if (tid < NBUCK) { h[tid] = 0; lcur[tid] = 0; }
    __syncthreads();

    int    rowv[16];
    uint32 pkx[16];
    float  vv[16];
    int base_e = blockIdx.x * EPB;
#pragma unroll
    for (int it = 0; it < 16; ++it) {
        int e = base_e + it * 256 + tid;
        if (e < NNZ_C) {
            int row = rows[e];
            int col = cols[e];
            int r   = (int)((uint32)col / (uint32)NN);
            int c   = col - r * NN;
            rowv[it] = row;
            pkx[it]  = (uint32)c | ((uint32)(((row & 255) << 4) | r) << 16);
            vv[it]   = vals[e];
            atomicAdd(&h[row >> 8], 1);
        } else rowv[it] = -1;
    }
    __syncthreads();
    if (tid < NBUCK && h[tid] > 0)
        gbase[tid] = atomicAdd(&cursor[tid], h[tid]);
    __syncthreads();
#pragma unroll
    for (int it = 0; it < 16; ++it) {
        if (rowv[it] >= 0) {
            int b   = rowv[it] >> 8;
            int pos = gbase[b] + atomicAdd(&lcur[b], 1);
            es2[pos] = make_uint2(pkx[it], __float_as_uint(vv[it]));
        }
    }
}

// ---------------------------------------------------------------------------
// Sort pass 4: one block per bucket — LDS counting-sort by sub-key
// kl = (row&255)*16 + r ; writes final es (x = c, y = val) and
// ks[b*4096 + kl] == ks[row*16 + r] = global segment start.
// ---------------------------------------------------------------------------
__global__ __launch_bounds__(256) void sortB_kernel(
        const uint2* __restrict__ es2,
        const int* __restrict__ bucket_start,
        uint2* __restrict__ es,
        int* __restrict__ ks) {
    __shared__ int h[4096];
    __shared__ int cur[4096];
    __shared__ int tmp[256];
    int b    = blockIdx.x;
    int tid  = threadIdx.x;
    int base = bucket_start[b];
    int n    = bucket_start[b + 1] - base;

#pragma unroll
    for (int j = 0; j < 16; ++j) h[j * 256 + tid] = 0;
    __syncthreads();
    for (int i = tid; i < n; i += 256) {
        uint2 p = es2[base + i];
        atomicAdd(&h[(p.x >> 16) & 0xfffu], 1);
    }
    __syncthreads();

    // block-wide exclusive scan over 4096 counters
    int run = 0;
    int loc[16];
#pragma unroll
    for (int j = 0; j < 16; ++j) {
        int c = h[tid * 16 + j];
        loc[j] = run;
        run += c;
    }
    tmp[tid] = run;
    __syncthreads();
#pragma unroll
    for (int off = 1; off < 256; off <<= 1) {
        int t = (tid >= off) ? tmp[tid - off] : 0;
        __syncthreads();
        tmp[tid] += t;
        __syncthreads();
    }
    int excl_t = tmp[tid] - run;
#pragma unroll
    for (int j = 0; j < 16; ++j) {
        int idx = tid * 16 + j;
        int st  = loc[j] + excl_t;
        cur[idx] = st;
        ks[b * 4096 + idx] = base + st;
    }
    __syncthreads();

    for (int i = tid; i < n; i += 256) {
        uint2 p  = es2[base + i];
        int   kl = (p.x >> 16) & 0xfffu;
        int  pos = atomicAdd(&cur[kl], 1);
        es[base + pos] = make_uint2(p.x & 0xffffu, p.y);
    }
}

// ---------------------------------------------------------------------------
// Yc build: one wave per row. Walk the row's (row,r)-sorted edges 4-deep
// pipelined, gathering bf16 X rows (cache-resident); flush one bf16 Yc
// slice per r (zeros for empty segments). YD is dword view of Yc half.
// ---------------------------------------------------------------------------
__global__ __launch_bounds__(256) void yc_build_kernel(
        const uint2* __restrict__ es,
        const int* __restrict__ ks,
        const uint32* __restrict__ XD,
        uint32* __restrict__ YD,
        int row0, int row_end) {
    int wid = blockIdx.x * 4 + (threadIdx.x >> 6);
    int row = row0 + wid;
    if (row >= row_end) return;
    int lane = threadIdx.x & 63;

    int s = (lane < 17) ? ks[row * 16 + lane] : 0;
    int beg     = __shfl(s, 0);
    int end_row = __shfl(s, 16);

    size_t yb = (size_t)(row - row0) * 1024;   // dwords per row = 2048 bf16
    float a0 = 0.f, a1 = 0.f;
    int r_cur = 0;
    int nxt = __shfl(s, 1);

    uint2 p0 = (beg + 0 < end_row) ? es[beg + 0] : make_uint2(0u, 0u);
    uint2 p1 = (beg + 1 < end_row) ? es[beg + 1] : make_uint2(0u, 0u);
    uint2 p2 = (beg + 2 < end_row) ? es[beg + 2] : make_uint2(0u, 0u);
    uint2 p3 = (beg + 3 < end_row) ? es[beg + 3] : make_uint2(0u, 0u);

#define CONSUME(P, XV, IDX)                                               \
    { int idx_ = (IDX);                                                   \
      while (idx_ >= nxt && r_cur < 16) {                                 \
          YD[yb + r_cur * 64 + lane] = pack_bf16(a0, a1);                 \
          a0 = a1 = 0.f; r_cur++;                                         \
          nxt = (r_cur < 16) ? __shfl(s, r_cur + 1) : 0x7fffffff;         \
      }                                                                   \
      if (idx_ < end_row) {                                               \
          float v_ = __uint_as_float((P).y);                              \
          a0 += v_ * bf2f((ushort16)((XV) & 0xffffu));                    \
          a1 += v_ * bf2f((ushort16)((XV) >> 16));                        \
      } }

    for (int e = beg; e < end_row; e += 4) {
        uint2 n0 = (e + 4 < end_row) ? es[e + 4] : make_uint2(0u, 0u);
        uint2 n1 = (e + 5 < end_row) ? es[e + 5] : make_uint2(0u, 0u);
        uint2 n2 = (e + 6 < end_row) ? es[e + 6] : make_uint2(0u, 0u);
        uint2 n3 = (e + 7 < end_row) ? es[e + 7] : make_uint2(0u, 0u);
        uint32 x0 = XD[((p0.x & 0xffffu) << 6) + lane];
        uint32 x1 = XD[((p1.x & 0xffffu) << 6) + lane];
        uint32 x2 = XD[((p2.x & 0xffffu) << 6) + lane];
        uint32 x3 = XD[((p3.x & 0xffffu) << 6) + lane];
        CONSUME(p0, x0, e + 0)
        CONSUME(p1, x1, e + 1)
        CONSUME(p2, x2, e + 2)
        CONSUME(p3, x3, e + 3)
        p0 = n0; p1 = n1; p2 = n2; p3 = n3;
    }
    while (r_cur < 16) {
        YD[yb + r_cur * 64 + lane] = pack_bf16(a0, a1);
        a0 = a1 = 0.f;
        r_cur++;
    }
#undef CONSUME
}

// ---------------------------------------------------------------------------
// Dense GEMM, barrier-free / LDS-free: out[row0+rl, jout] = sum_rk
// Ych[rl, rk] * Wst[jout, rk]. Block = 32 rows x 128 jout, 4 waves:
// wave (rgrp,jgrp) covers rows rgrp*16..+16, jout jgrp*64..+64 (4 acc tiles).
// A-frags stream from Ych (16B/lane, full 64B lines), B-frags from L2-hot
// Wst. No __syncthreads anywhere -> compiler pipelines K-loop freely.
// ---------------------------------------------------------------------------
__global__ __launch_bounds__(256) void gemm_out_kernel(
        const ushort16* __restrict__ Ych,
        const ushort16* __restrict__ Wst,
        float* __restrict__ out,
        int row0, int rowmax) {
    const int tid  = threadIdx.x;
    const int wave = tid >> 6;          // 0..3
    const int lane = tid & 63;
    const int m    = lane & 15;
    const int half = lane >> 4;
    const int rgrp = wave >> 1;
    const int jgrp = wave & 1;
    const int rb_local = blockIdx.x * 32 + rgrp * 16;
    const int nlocal   = rowmax - row0;

    int rl = rb_local + m;
    if (rl >= nlocal) rl = nlocal - 1;   // clamp; epilogue guards stores

    const ushort16* arow = Ych + (size_t)rl * KK + half * 8;
    const ushort16* brow = Wst + (size_t)(jgrp * 64 + m) * KK + half * 8;

    floatx4 acc[4] = {};
#pragma unroll 4
    for (int sl = 0; sl < 64; ++sl) {
        short8 af = *(const short8*)(arow + sl * 32);
#pragma unroll
        for (int t = 0; t < 4; ++t) {
            short8 bf = *(const short8*)(brow + (size_t)(t * 16) * KK + sl * 32);
            acc[t] = __builtin_amdgcn_mfma_f32_16x16x32_bf16(af, bf, acc[t], 0, 0, 0);
        }
    }

    // C/D layout: col = t*16+m (within jgrp*64), tile-row = half*4+reg
#pragma unroll
    for (int t = 0; t < 4; ++t) {
#pragma unroll
        for (int reg = 0; reg < 4; ++reg) {
            int grow = row0 + rb_local + half * 4 + reg;
            if (grow < rowmax)
                out[(size_t)grow * DOUT + jgrp * 64 + t * 16 + m] = acc[t][reg];
        }
    }
}

// ---------------------------------------------------------------------------
extern "C" void kernel_launch(void* const* d_in, const int* in_sizes, int n_in,
                              void* d_out, int out_size, void* d_ws, size_t ws_size,
                              hipStream_t stream) {
    const float* X      = (const float*)d_in[0];
    const int*   A_rows = (const int*)d_in[1];
    const int*   A_cols = (const int*)d_in[2];
    const float* A_vals = (const float*)d_in[3];
    const float* basis  = (const float*)d_in[4];
    const float* comp   = (const float*)d_in[5];
    float* out = (float*)d_out;

    // workspace layout (peak 131.9 MB)
    char* ws = (char*)d_ws;
    ushort16* Wst          = (ushort16*)(ws + 0);            // 512 KB
    uint32*   XD           = (uint32*)(ws + 524288);         // 12.8 MB
    int*      ks           = (int*)(ws + 13324288);          // 802816 ints
    uint2*    es           = (uint2*)(ws + 16535552);        // 12.8 MB
    int*      bucket_start = (int*)(ws + 29335552);          // 197 ints
    int*      counts       = (int*)(ws + 29336576);          // 196 ints
    int*      cursor       = (int*)(ws + 29337600);          // 196 ints
    uint2*    es2          = (uint2*)(ws + 29339648);        // 12.8 MB
    ushort16* Ych          = (ushort16*)(ws + 29339648);     // 102.5 MB (reuses es2 after sortB)
    uint32*   YD           = (uint32*)Ych;

    hipMemsetAsync(counts, 0, NBUCK * sizeof(int), stream);

    build_wst_kernel<<<1024, 256, 0, stream>>>(basis, comp, Wst);
    cvt_x_kernel<<<12500, 256, 0, stream>>>(X, XD);

    histB_kernel<<<NBLK_E, 256, 0, stream>>>(A_rows, counts);
    scanB_kernel<<<1, 256, 0, stream>>>(counts, bucket_start, cursor);
    scatterB_kernel<<<NBLK_E, 256, 0, stream>>>(A_rows, A_cols, A_vals,
                                                cursor, es2);
    sortB_kernel<<<NBUCK, 256, 0, stream>>>(es2, bucket_start, es, ks);

    // phase 1: rows [0, ROWSPLIT)
    yc_build_kernel<<<ROWSPLIT / 4, 256, 0, stream>>>(es, ks, XD, YD, 0, ROWSPLIT);
    gemm_out_kernel<<<ROWSPLIT / 32, 256, 0, stream>>>(Ych, Wst, out, 0, ROWSPLIT);

    // phase 2: rows [ROWSPLIT, NN)
    int rows2 = NN - ROWSPLIT;                       // 24976
    yc_build_kernel<<<rows2 / 4, 256, 0, stream>>>(es, ks, XD, YD, ROWSPLIT, NN);
    gemm_out_kernel<<<(rows2 + 31) / 32, 256, 0, stream>>>(Ych, Wst, out, ROWSPLIT, NN);
}

// Round 8
// 277.065 us; speedup vs baseline: 3.0877x; 1.9789x over previous
//
#include <hip/hip_runtime.h>

typedef unsigned int   uint32;
typedef unsigned short ushort16;

#define NN       50000
#define RR       16
#define BB       8
#define DIN      128
#define DOUT     128
#define K2       1024          // B*DIN (basis-combined K)
#define NNZ_C    1600000
#define NBUCK    196           // row>>8 buckets (256 rows each)
#define EPB      4096          // edges per block in sort passes
#define NBLK_E   391           // ceil(NNZ/EPB)

typedef short  short8  __attribute__((ext_vector_type(8)));
typedef float  floatx4 __attribute__((ext_vector_type(4)));

__device__ __forceinline__ ushort16 f2bf(float f) {
    uint32 u = __float_as_uint(f);
    u += 0x7fffu + ((u >> 16) & 1u);   // RNE
    return (ushort16)(u >> 16);
}

__device__ __forceinline__ float bf2f(ushort16 h) {
    return __uint_as_float(((uint32)h) << 16);
}

// pack two f32 -> (bf16(b)<<16)|bf16(a), round-half-up
__device__ __forceinline__ uint32 pack_bf16(float a, float b) {
    uint32 ua = __float_as_uint(a) + 0x8000u;
    uint32 ub = __float_as_uint(b) + 0x8000u;
    return __builtin_amdgcn_perm(ub, ua, 0x07060302);
}

// async global->LDS, 16B per lane; LDS dest = uniform base + lane*16
__device__ __forceinline__ void gload16(const void* g, void* l) {
    __builtin_amdgcn_global_load_lds(
        (const __attribute__((address_space(1))) uint32*)g,
        (__attribute__((address_space(3))) uint32*)l, 16, 0, 0);
}

// ---------------------------------------------------------------------------
// Bst[jout][b*128+jin] = basis[b][jin][jout]   (bf16 transpose-cast)
// ---------------------------------------------------------------------------
__global__ void build_bst_kernel(const float* __restrict__ basis,
                                 ushort16* __restrict__ Bst) {
    int idx  = blockIdx.x * 256 + threadIdx.x;   // 128*1024 = 131072
    int jout = idx >> 10;
    int bk   = idx & 1023;           // b*128 + jin
    Bst[idx] = f2bf(basis[(size_t)bk * DOUT + jout]);
}

// ---------------------------------------------------------------------------
// X (f32, N x 128) -> XD (bf16 packed dwords, N x 64 dwords)
// ---------------------------------------------------------------------------
__global__ void cvt_x_kernel(const float* __restrict__ X,
                             uint32* __restrict__ XD) {
    int d = blockIdx.x * 256 + threadIdx.x;      // 3,200,000 dwords
    float2 f = *(const float2*)(X + (size_t)d * 2);
    XD[d] = pack_bf16(f.x, f.y);
}

// ---------------------------------------------------------------------------
// Sort pass 1: global bucket histogram (LDS-aggregated)
// ---------------------------------------------------------------------------
__global__ void histB_kernel(const int* __restrict__ rows,
                             int* __restrict__ counts) {
    __shared__ int h[NBUCK];
    int tid = threadIdx.x;
    if (tid < NBUCK) h[tid] = 0;
    __syncthreads();
    int base_e = blockIdx.x * EPB;
#pragma unroll
    for (int it = 0; it < 16; ++it) {
        int e = base_e + it * 256 + tid;
        if (e < NNZ_C) atomicAdd(&h[rows[e] >> 8], 1);
    }
    __syncthreads();
    if (tid < NBUCK && h[tid]) atomicAdd(&counts[tid], h[tid]);
}

// ---------------------------------------------------------------------------
// Sort pass 2: scan 196 bucket counts (single block); init cursors
// ---------------------------------------------------------------------------
__global__ void scanB_kernel(const int* __restrict__ counts,
                             int* __restrict__ bucket_start,
                             int* __restrict__ cursor) {
    __shared__ int tmp[256];
    int tid = threadIdx.x;
    int v = (tid < NBUCK) ? counts[tid] : 0;
    tmp[tid] = v;
    __syncthreads();
#pragma unroll
    for (int off = 1; off < 256; off <<= 1) {
        int t = (tid >= off) ? tmp[tid - off] : 0;
        __syncthreads();
        tmp[tid] += t;
        __syncthreads();
    }
    if (tid < NBUCK) {
        bucket_start[tid + 1] = tmp[tid];          // inclusive
        cursor[tid] = tmp[tid] - v;                // exclusive
        if (tid == 0) bucket_start[0] = 0;
    }
}

// ---------------------------------------------------------------------------
// Sort pass 3: per-block range reservation + scatter into bucket-grouped es2.
// payload x = c(16b) | kl(12b)<<16, kl = (row&255)*16 + r ; y = val bits
// ---------------------------------------------------------------------------
__global__ __launch_bounds__(256) void scatterB_kernel(
        const int* __restrict__ rows,
        const int* __restrict__ cols,
        const float* __restrict__ vals,
        int* __restrict__ cursor,
        uint2* __restrict__ es2) {
    __shared__ int h[NBUCK], gbase[NBUCK], lcur[NBUCK];
    int tid = threadIdx.x;
    if (tid < NBUCK) { h[tid] = 0; lcur[tid] = 0; }
    __syncthreads();

    int    rowv[16];
    uint32 pkx[16];
    float  vv[16];
    int base_e = blockIdx.x * EPB;
#pragma unroll
    for (int it = 0; it < 16; ++it) {
        int e = base_e + it * 256 + tid;
        if (e < NNZ_C) {
            int row = rows[e];
            int col = cols[e];
            int r   = (int)((uint32)col / (uint32)NN);
            int c   = col - r * NN;
            rowv[it] = row;
            pkx[it]  = (uint32)c | ((uint32)(((row & 255) << 4) | r) << 16);
            vv[it]   = vals[e];
            atomicAdd(&h[row >> 8], 1);
        } else rowv[it] = -1;
    }
    __syncthreads();
    if (tid < NBUCK && h[tid] > 0)
        gbase[tid] = atomicAdd(&cursor[tid], h[tid]);
    __syncthreads();
#pragma unroll
    for (int it = 0; it < 16; ++it) {
        if (rowv[it] >= 0) {
            int b   = rowv[it] >> 8;
            int pos = gbase[b] + atomicAdd(&lcur[b], 1);
            es2[pos] = make_uint2(pkx[it], __float_as_uint(vv[it]));
        }
    }
}

// ---------------------------------------------------------------------------
// Sort pass 4: one block per bucket — LDS counting-sort by sub-key
// kl = (row&255)*16 + r ; writes final es (x = c, y = val) and
// ks[b*4096 + kl] == ks[row*16 + r] = global segment start.
// ---------------------------------------------------------------------------
__global__ __launch_bounds__(256) void sortB_kernel(
        const uint2* __restrict__ es2,
        const int* __restrict__ bucket_start,
        uint2* __restrict__ es,
        int* __restrict__ ks) {
    __shared__ int h[4096];
    __shared__ int cur[4096];
    __shared__ int tmp[256];
    int b    = blockIdx.x;
    int tid  = threadIdx.x;
    int base = bucket_start[b];
    int n    = bucket_start[b + 1] - base;

#pragma unroll
    for (int j = 0; j < 16; ++j) h[j * 256 + tid] = 0;
    __syncthreads();
    for (int i = tid; i < n; i += 256) {
        uint2 p = es2[base + i];
        atomicAdd(&h[(p.x >> 16) & 0xfffu], 1);
    }
    __syncthreads();

    // block-wide exclusive scan over 4096 counters
    int run = 0;
    int loc[16];
#pragma unroll
    for (int j = 0; j < 16; ++j) {
        int c = h[tid * 16 + j];
        loc[j] = run;
        run += c;
    }
    tmp[tid] = run;
    __syncthreads();
#pragma unroll
    for (int off = 1; off < 256; off <<= 1) {
        int t = (tid >= off) ? tmp[tid - off] : 0;
        __syncthreads();
        tmp[tid] += t;
        __syncthreads();
    }
    int excl_t = tmp[tid] - run;
#pragma unroll
    for (int j = 0; j < 16; ++j) {
        int idx = tid * 16 + j;
        int st  = loc[j] + excl_t;
        cur[idx] = st;
        ks[b * 4096 + idx] = base + st;
    }
    __syncthreads();

    for (int i = tid; i < n; i += 256) {
        uint2 p  = es2[base + i];
        int   kl = (p.x >> 16) & 0xfffu;
        int  pos = atomicAdd(&cur[kl], 1);
        es[base + pos] = make_uint2(p.x & 0xffffu, p.y);
    }
}

// ---------------------------------------------------------------------------
// Zc build (basis-combined): one wave per row. Walk the (row,r)-sorted edges
// 4-deep pipelined; per-(row,r) segment accumulates in regs, FLUSH folds it
// into 8 comp-weighted basis accumulators; write the 1024-wide bf16 Zc row
// once at the end.  Zc[row][b*128 + j] = sum_r comp[r,b] * seg_{row,r}[j].
// ---------------------------------------------------------------------------
__global__ __launch_bounds__(256) void zc_build_kernel(
        const uint2* __restrict__ es,
        const int* __restrict__ ks,
        const uint32* __restrict__ XD,
        const float* __restrict__ comp,
        uint32* __restrict__ ZD) {
    __shared__ float comp_l[128];
    int tid = threadIdx.x;
    if (tid < 128) comp_l[tid] = comp[tid];
    __syncthreads();

    int row  = blockIdx.x * 4 + (tid >> 6);     // grid 12500 -> rows < 50000
    int lane = tid & 63;

    int s = (lane < 17) ? ks[row * 16 + lane] : 0;
    int beg     = __shfl(s, 0);
    int end_row = __shfl(s, 16);

    float zb0[8] = {0.f,0.f,0.f,0.f,0.f,0.f,0.f,0.f};
    float zb1[8] = {0.f,0.f,0.f,0.f,0.f,0.f,0.f,0.f};
    float a0 = 0.f, a1 = 0.f;
    int r_cur = 0;
    int nxt = __shfl(s, 1);

    uint2 p0 = (beg + 0 < end_row) ? es[beg + 0] : make_uint2(0u, 0u);
    uint2 p1 = (beg + 1 < end_row) ? es[beg + 1] : make_uint2(0u, 0u);
    uint2 p2 = (beg + 2 < end_row) ? es[beg + 2] : make_uint2(0u, 0u);
    uint2 p3 = (beg + 3 < end_row) ? es[beg + 3] : make_uint2(0u, 0u);

#define FLUSH                                                             \
    { _Pragma("unroll")                                                   \
      for (int b = 0; b < 8; ++b) {                                       \
          float cb = comp_l[r_cur * 8 + b];                               \
          zb0[b] += cb * a0; zb1[b] += cb * a1;                           \
      }                                                                   \
      a0 = a1 = 0.f; r_cur++;                                             \
      nxt = (r_cur < 16) ? __shfl(s, r_cur + 1) : 0x7fffffff; }

#define CONSUME(P, XV, IDX)                                               \
    { int idx_ = (IDX);                                                   \
      while (idx_ >= nxt && r_cur < 16) FLUSH                             \
      if (idx_ < end_row) {                                               \
          float v_ = __uint_as_float((P).y);                              \
          a0 += v_ * bf2f((ushort16)((XV) & 0xffffu));                    \
          a1 += v_ * bf2f((ushort16)((XV) >> 16));                        \
      } }

    for (int e = beg; e < end_row; e += 4) {
        uint2 n0 = (e + 4 < end_row) ? es[e + 4] : make_uint2(0u, 0u);
        uint2 n1 = (e + 5 < end_row) ? es[e + 5] : make_uint2(0u, 0u);
        uint2 n2 = (e + 6 < end_row) ? es[e + 6] : make_uint2(0u, 0u);
        uint2 n3 = (e + 7 < end_row) ? es[e + 7] : make_uint2(0u, 0u);
        uint32 x0 = XD[((p0.x & 0xffffu) << 6) + lane];
        uint32 x1 = XD[((p1.x & 0xffffu) << 6) + lane];
        uint32 x2 = XD[((p2.x & 0xffffu) << 6) + lane];
        uint32 x3 = XD[((p3.x & 0xffffu) << 6) + lane];
        CONSUME(p0, x0, e + 0)
        CONSUME(p1, x1, e + 1)
        CONSUME(p2, x2, e + 2)
        CONSUME(p3, x3, e + 3)
        p0 = n0; p1 = n1; p2 = n2; p3 = n3;
    }
    while (r_cur < 16) FLUSH

#pragma unroll
    for (int b = 0; b < 8; ++b)
        ZD[(size_t)row * 512 + b * 64 + lane] = pack_bf16(zb0[b], zb1[b]);
#undef CONSUME
#undef FLUSH
}

// ---------------------------------------------------------------------------
// Dense GEMM (m97-style): out[n, jout] = sum_k Zc[n, k] * Bst[jout, k].
// Block = 128 rows x 128 jout, 256 thr (4 waves, 2x2), K=1024 in 16 BK=64
// slabs. A+B staged via global_load_lds(16B); fragment reads ds_read_b128
// with XOR chunk-swizzle p = row*8 + (kc ^ (row&7)) -> 2-way banks (free).
// ---------------------------------------------------------------------------
__global__ __launch_bounds__(256) void gemm_out_kernel(
        const ushort16* __restrict__ Zc,
        const ushort16* __restrict__ Bst,
        float* __restrict__ out) {
    __shared__ __align__(16) char lds[32768];
    char* Al = lds;               // 16 KB: A slab 128 rows x 64 k
    char* Bl = lds + 16384;       // 16 KB: B slab 128 jout x 64 k

    const int tid  = threadIdx.x;
    const int wave = tid >> 6;
    const int lane = tid & 63;
    const int m    = lane & 15;
    const int half = lane >> 4;
    const int wr   = wave >> 1;          // row half of block
    const int wc   = wave & 1;           // col half of block
    const size_t arow0 = (size_t)blockIdx.x * 128;

    floatx4 acc[16] = {};

    for (int slab = 0; slab < 16; ++slab) {
        const int k0 = slab * 64;
        // stage: physical chunk s holds (row = s>>3, kc = (s&7)^(row&7))
#pragma unroll
        for (int rd = 0; rd < 4; ++rd) {
            int s   = rd * 256 + wave * 64 + lane;
            int row = s >> 3;
            int kc  = (s & 7) ^ (row & 7);
            size_t ldsoff = (size_t)(rd * 256 + wave * 64) * 16;
            gload16(Zc  + ((arow0 + row) << 10) + k0 + (kc << 3), Al + ldsoff);
            gload16(Bst + ((size_t)row << 10)   + k0 + (kc << 3), Bl + ldsoff);
        }
        __syncthreads();

#pragma unroll
        for (int c = 0; c < 2; ++c) {
            short8 a[4], bfr[4];
#pragma unroll
            for (int mt = 0; mt < 4; ++mt) {
                int row = wr * 64 + mt * 16 + m;
                int p   = row * 8 + ((c * 4 + half) ^ (m & 7));
                a[mt] = *(const short8*)(Al + p * 16);
            }
#pragma unroll
            for (int nt = 0; nt < 4; ++nt) {
                int rowb = wc * 64 + nt * 16 + m;
                int p    = rowb * 8 + ((c * 4 + half) ^ (m & 7));
                bfr[nt] = *(const short8*)(Bl + p * 16);
            }
#pragma unroll
            for (int mt = 0; mt < 4; ++mt)
#pragma unroll
                for (int nt = 0; nt < 4; ++nt)
                    acc[mt * 4 + nt] = __builtin_amdgcn_mfma_f32_16x16x32_bf16(
                        a[mt], bfr[nt], acc[mt * 4 + nt], 0, 0, 0);
        }
        __syncthreads();
    }

    // epilogue: C/D layout col = m (jout tile), row = half*4 + reg
#pragma unroll
    for (int mt = 0; mt < 4; ++mt) {
#pragma unroll
        for (int reg = 0; reg < 4; ++reg) {
            int grow = (int)arow0 + wr * 64 + mt * 16 + half * 4 + reg;
            if (grow < NN) {
#pragma unroll
                for (int nt = 0; nt < 4; ++nt)
                    out[(size_t)grow * DOUT + wc * 64 + nt * 16 + m] =
                        acc[mt * 4 + nt][reg];
            }
        }
    }
}

// ---------------------------------------------------------------------------
extern "C" void kernel_launch(void* const* d_in, const int* in_sizes, int n_in,
                              void* d_out, int out_size, void* d_ws, size_t ws_size,
                              hipStream_t stream) {
    const float* X      = (const float*)d_in[0];
    const int*   A_rows = (const int*)d_in[1];
    const int*   A_cols = (const int*)d_in[2];
    const float* A_vals = (const float*)d_in[3];
    const float* basis  = (const float*)d_in[4];
    const float* comp   = (const float*)d_in[5];
    float* out = (float*)d_out;

    // workspace layout (peak ~144.6 MB, under the proven 218.7 MB budget)
    char* ws = (char*)d_ws;
    ushort16* Bst          = (ushort16*)(ws + 0);            // 256 KB
    uint32*   XD           = (uint32*)(ws + 524288);         // 12.8 MB
    int*      ks           = (int*)(ws + 13324288);          // 802816 ints
    uint2*    es           = (uint2*)(ws + 16535552);        // 12.8 MB
    int*      bucket_start = (int*)(ws + 29335552);          // 197 ints
    int*      counts       = (int*)(ws + 29336576);          // 196 ints
    int*      cursor       = (int*)(ws + 29337600);          // 196 ints
    uint2*    es2          = (uint2*)(ws + 29339648);        // 12.8 MB
    ushort16* Zc           = (ushort16*)(ws + 42139648);     // 102.4 MB
    uint32*   ZD           = (uint32*)Zc;

    hipMemsetAsync(counts, 0, NBUCK * sizeof(int), stream);

    build_bst_kernel<<<512, 256, 0, stream>>>(basis, Bst);
    cvt_x_kernel<<<12500, 256, 0, stream>>>(X, XD);

    histB_kernel<<<NBLK_E, 256, 0, stream>>>(A_rows, counts);
    scanB_kernel<<<1, 256, 0, stream>>>(counts, bucket_start, cursor);
    scatterB_kernel<<<NBLK_E, 256, 0, stream>>>(A_rows, A_cols, A_vals,
                                                cursor, es2);
    sortB_kernel<<<NBUCK, 256, 0, stream>>>(es2, bucket_start, es, ks);

    zc_build_kernel<<<12500, 256, 0, stream>>>(es, ks, XD, comp, ZD);

    gemm_out_kernel<<<(NN + 127) / 128, 256, 0, stream>>>(Zc, Bst, out);
}

// Round 9
// 260.459 us; speedup vs baseline: 3.2846x; 1.0638x over previous
//
#include <hip/hip_runtime.h>

typedef unsigned int   uint32;
typedef unsigned short ushort16;

#define NN       50000
#define RR       16
#define BB       8
#define DIN      128
#define DOUT     128
#define K2       1024          // B*DIN (basis-combined K)
#define NNZ_C    1600000
#define NBUCK    196           // row>>8 buckets (256 rows each)
#define EPB      4096          // edges per block in sort passes
#define NBLK_E   391           // ceil(NNZ/EPB)

typedef short  short8  __attribute__((ext_vector_type(8)));
typedef float  floatx4 __attribute__((ext_vector_type(4)));
typedef float  float2v __attribute__((ext_vector_type(2)));

__device__ __forceinline__ ushort16 f2bf(float f) {
    uint32 u = __float_as_uint(f);
    u += 0x7fffu + ((u >> 16) & 1u);   // RNE
    return (ushort16)(u >> 16);
}

__device__ __forceinline__ float bf2f(ushort16 h) {
    return __uint_as_float(((uint32)h) << 16);
}

// pack two f32 -> (bf16(b)<<16)|bf16(a), round-half-up
__device__ __forceinline__ uint32 pack_bf16(float a, float b) {
    uint32 ua = __float_as_uint(a) + 0x8000u;
    uint32 ub = __float_as_uint(b) + 0x8000u;
    return __builtin_amdgcn_perm(ub, ua, 0x07060302);
}

// async global->LDS, 16B per lane; LDS dest = uniform base + lane*16
__device__ __forceinline__ void gload16(const void* g, void* l) {
    __builtin_amdgcn_global_load_lds(
        (const __attribute__((address_space(1))) uint32*)g,
        (__attribute__((address_space(3))) uint32*)l, 16, 0, 0);
}

// ---------------------------------------------------------------------------
// Bst[jout][b*128+jin] = basis[b][jin][jout]   (bf16 transpose-cast)
// ---------------------------------------------------------------------------
__global__ void build_bst_kernel(const float* __restrict__ basis,
                                 ushort16* __restrict__ Bst) {
    int idx  = blockIdx.x * 256 + threadIdx.x;   // 128*1024 = 131072
    int jout = idx >> 10;
    int bk   = idx & 1023;           // b*128 + jin
    Bst[idx] = f2bf(basis[(size_t)bk * DOUT + jout]);
}

// ---------------------------------------------------------------------------
// X (f32, N x 128) -> XD (bf16 packed dwords, N x 64 dwords)
// ---------------------------------------------------------------------------
__global__ void cvt_x_kernel(const float* __restrict__ X,
                             uint32* __restrict__ XD) {
    int d = blockIdx.x * 256 + threadIdx.x;      // 3,200,000 dwords
    float2 f = *(const float2*)(X + (size_t)d * 2);
    XD[d] = pack_bf16(f.x, f.y);
}

// ---------------------------------------------------------------------------
// Sort pass 1: global bucket histogram (LDS-aggregated)
// ---------------------------------------------------------------------------
__global__ void histB_kernel(const int* __restrict__ rows,
                             int* __restrict__ counts) {
    __shared__ int h[NBUCK];
    int tid = threadIdx.x;
    if (tid < NBUCK) h[tid] = 0;
    __syncthreads();
    int base_e = blockIdx.x * EPB;
#pragma unroll
    for (int it = 0; it < 16; ++it) {
        int e = base_e + it * 256 + tid;
        if (e < NNZ_C) atomicAdd(&h[rows[e] >> 8], 1);
    }
    __syncthreads();
    if (tid < NBUCK && h[tid]) atomicAdd(&counts[tid], h[tid]);
}

// ---------------------------------------------------------------------------
// Sort pass 2: scan 196 bucket counts (single block); init cursors
// ---------------------------------------------------------------------------
__global__ void scanB_kernel(const int* __restrict__ counts,
                             int* __restrict__ bucket_start,
                             int* __restrict__ cursor) {
    __shared__ int tmp[256];
    int tid = threadIdx.x;
    int v = (tid < NBUCK) ? counts[tid] : 0;
    tmp[tid] = v;
    __syncthreads();
#pragma unroll
    for (int off = 1; off < 256; off <<= 1) {
        int t = (tid >= off) ? tmp[tid - off] : 0;
        __syncthreads();
        tmp[tid] += t;
        __syncthreads();
    }
    if (tid < NBUCK) {
        bucket_start[tid + 1] = tmp[tid];          // inclusive
        cursor[tid] = tmp[tid] - v;                // exclusive
        if (tid == 0) bucket_start[0] = 0;
    }
}

// ---------------------------------------------------------------------------
// Sort pass 3: per-block range reservation + scatter into bucket-grouped es2.
// payload x = c(16b) | kl(12b)<<16, kl = (row&255)*16 + r ; y = val bits
// ---------------------------------------------------------------------------
__global__ __launch_bounds__(256) void scatterB_kernel(
        const int* __restrict__ rows,
        const int* __restrict__ cols,
        const float* __restrict__ vals,
        int* __restrict__ cursor,
        uint2* __restrict__ es2) {
    __shared__ int h[NBUCK], gbase[NBUCK], lcur[NBUCK];
    int tid = threadIdx.x;
    if (tid < NBUCK) { h[tid] = 0; lcur[tid] = 0; }
    __syncthreads();

    int    rowv[16];
    uint32 pkx[16];
    float  vv[16];
    int base_e = blockIdx.x * EPB;
#pragma unroll
    for (int it = 0; it < 16; ++it) {
        int e = base_e + it * 256 + tid;
        if (e < NNZ_C) {
            int row = rows[e];
            int col = cols[e];
            int r   = (int)((uint32)col / (uint32)NN);
            int c   = col - r * NN;
            rowv[it] = row;
            pkx[it]  = (uint32)c | ((uint32)(((row & 255) << 4) | r) << 16);
            vv[it]   = vals[e];
            atomicAdd(&h[row >> 8], 1);
        } else rowv[it] = -1;
    }
    __syncthreads();
    if (tid < NBUCK && h[tid] > 0)
        gbase[tid] = atomicAdd(&cursor[tid], h[tid]);
    __syncthreads();
#pragma unroll
    for (int it = 0; it < 16; ++it) {
        if (rowv[it] >= 0) {
            int b   = rowv[it] >> 8;
            int pos = gbase[b] + atomicAdd(&lcur[b], 1);
            es2[pos] = make_uint2(pkx[it], __float_as_uint(vv[it]));
        }
    }
}

// ---------------------------------------------------------------------------
// Sort pass 4: one block per bucket — LDS counting-sort by sub-key
// kl = (row&255)*16 + r ; writes final es (x = c | r<<16, y = val) and
// ks[b*4096 + kl] == ks[row*16 + r] = global segment start.
// ---------------------------------------------------------------------------
__global__ __launch_bounds__(256) void sortB_kernel(
        const uint2* __restrict__ es2,
        const int* __restrict__ bucket_start,
        uint2* __restrict__ es,
        int* __restrict__ ks) {
    __shared__ int h[4096];
    __shared__ int cur[4096];
    __shared__ int tmp[256];
    int b    = blockIdx.x;
    int tid  = threadIdx.x;
    int base = bucket_start[b];
    int n    = bucket_start[b + 1] - base;

#pragma unroll
    for (int j = 0; j < 16; ++j) h[j * 256 + tid] = 0;
    __syncthreads();
    for (int i = tid; i < n; i += 256) {
        uint2 p = es2[base + i];
        atomicAdd(&h[(p.x >> 16) & 0xfffu], 1);
    }
    __syncthreads();

    // block-wide exclusive scan over 4096 counters
    int run = 0;
    int loc[16];
#pragma unroll
    for (int j = 0; j < 16; ++j) {
        int c = h[tid * 16 + j];
        loc[j] = run;
        run += c;
    }
    tmp[tid] = run;
    __syncthreads();
#pragma unroll
    for (int off = 1; off < 256; off <<= 1) {
        int t = (tid >= off) ? tmp[tid - off] : 0;
        __syncthreads();
        tmp[tid] += t;
        __syncthreads();
    }
    int excl_t = tmp[tid] - run;
#pragma unroll
    for (int j = 0; j < 16; ++j) {
        int idx = tid * 16 + j;
        int st  = loc[j] + excl_t;
        cur[idx] = st;
        ks[b * 4096 + idx] = base + st;
    }
    __syncthreads();

    for (int i = tid; i < n; i += 256) {
        uint2 p  = es2[base + i];
        int   kl = (p.x >> 16) & 0xfffu;
        int  pos = atomicAdd(&cur[kl], 1);
        // final payload keeps r (= kl&15) in bits 16..19
        es[base + pos] = make_uint2((p.x & 0xffffu) | ((uint32)(kl & 15) << 16),
                                    p.y);
    }
}

// ---------------------------------------------------------------------------
// Zc build, scalarized: one wave per row. Edge stream is (row,r)-sorted with
// r embedded in es.x[19:16]; records are wave-uniform -> readfirstlane puts
// ALL control (bounds, r-switch detection, fold triggering) on the SALU pipe.
// Per edge: 1 coalesced 256B X-row gather (scalar base + lane*4) + 1 packed
// FMA. Fold into 8 comp-weighted basis accumulators only when r changes.
// ---------------------------------------------------------------------------
__global__ __launch_bounds__(256) void zc_build_kernel(
        const uint2* __restrict__ es,
        const int* __restrict__ ks,
        const uint32* __restrict__ XD,
        const float* __restrict__ comp,
        uint32* __restrict__ ZD) {
    __shared__ __align__(16) float comp_l[128];
    int tid = threadIdx.x;
    if (tid < 128) comp_l[tid] = comp[tid];
    __syncthreads();

    const int row  = __builtin_amdgcn_readfirstlane(blockIdx.x * 4 + (tid >> 6));
    const int lane = tid & 63;

    int beg = __builtin_amdgcn_readfirstlane(ks[row * 16]);
    int end = __builtin_amdgcn_readfirstlane(ks[row * 16 + 16]); // ==NNZ for last row

    float2v zb[8];
#pragma unroll
    for (int b = 0; b < 8; ++b) zb[b] = (float2v){0.f, 0.f};

    if (beg < end) {
        const int endm1 = end - 1;
        float2v a = (float2v){0.f, 0.f};

#define LREC(C, R, V, IDX)                                                 \
        { int i_ = (IDX) < endm1 ? (IDX) : endm1;                          \
          uint2 pz_ = es[i_];                                              \
          uint32 px_ = __builtin_amdgcn_readfirstlane(pz_.x);              \
          V = __uint_as_float(__builtin_amdgcn_readfirstlane(pz_.y));      \
          C = (int)(px_ & 0xffffu); R = (int)(px_ >> 16); }

#define LX(X, C)  X = XD[((size_t)(C) << 6) + lane];

#define FOLD                                                               \
        { float4 c0_ = *(const float4*)&comp_l[r_cur * 8];                 \
          float4 c1_ = *(const float4*)&comp_l[r_cur * 8 + 4];             \
          zb[0] += c0_.x * a; zb[1] += c0_.y * a;                          \
          zb[2] += c0_.z * a; zb[3] += c0_.w * a;                          \
          zb[4] += c1_.x * a; zb[5] += c1_.y * a;                          \
          zb[6] += c1_.z * a; zb[7] += c1_.w * a; }

#define CONS(R, V, X, K)                                                   \
        if (e + (K) < end) {                                               \
            if ((R) != r_cur) {                                            \
                FOLD                                                       \
                a = (float2v){0.f, 0.f};                                   \
                r_cur = (R);                                               \
            }                                                              \
            float2v xf_;                                                   \
            xf_.x = __uint_as_float((X) << 16);                            \
            xf_.y = __uint_as_float((X) & 0xffff0000u);                    \
            a += (V) * xf_;                                                \
        }

        int   cA0, cA1, cA2, cA3, rA0, rA1, rA2, rA3;
        int   cB0, cB1, cB2, cB3, rB0, rB1, rB2, rB3;
        float vA0, vA1, vA2, vA3, vB0, vB1, vB2, vB3;
        uint32 xA0, xA1, xA2, xA3;

        LREC(cA0, rA0, vA0, beg + 0)
        LREC(cA1, rA1, vA1, beg + 1)
        LREC(cA2, rA2, vA2, beg + 2)
        LREC(cA3, rA3, vA3, beg + 3)
        LREC(cB0, rB0, vB0, beg + 4)
        LREC(cB1, rB1, vB1, beg + 5)
        LREC(cB2, rB2, vB2, beg + 6)
        LREC(cB3, rB3, vB3, beg + 7)
        LX(xA0, cA0) LX(xA1, cA1) LX(xA2, cA2) LX(xA3, cA3)

        int r_cur = rA0;

        for (int e = beg; e < end; e += 8) {
            uint32 xB0, xB1, xB2, xB3;
            LX(xB0, cB0) LX(xB1, cB1) LX(xB2, cB2) LX(xB3, cB3)
            int cC0, cC1, cC2, cC3, rC0, rC1, rC2, rC3;
            float vC0, vC1, vC2, vC3;
            LREC(cC0, rC0, vC0, e + 8)
            LREC(cC1, rC1, vC1, e + 9)
            LREC(cC2, rC2, vC2, e + 10)
            LREC(cC3, rC3, vC3, e + 11)

            CONS(rA0, vA0, xA0, 0)
            CONS(rA1, vA1, xA1, 1)
            CONS(rA2, vA2, xA2, 2)
            CONS(rA3, vA3, xA3, 3)

            uint32 xC0, xC1, xC2, xC3;
            LX(xC0, cC0) LX(xC1, cC1) LX(xC2, cC2) LX(xC3, cC3)
            int cD0, cD1, cD2, cD3, rD0, rD1, rD2, rD3;
            float vD0, vD1, vD2, vD3;
            LREC(cD0, rD0, vD0, e + 12)
            LREC(cD1, rD1, vD1, e + 13)
            LREC(cD2, rD2, vD2, e + 14)
            LREC(cD3, rD3, vD3, e + 15)

            CONS(rB0, vB0, xB0, 4)
            CONS(rB1, vB1, xB1, 5)
            CONS(rB2, vB2, xB2, 6)
            CONS(rB3, vB3, xB3, 7)

            // rotate C->A (records + x), D->B (records)
            cA0 = cC0; cA1 = cC1; cA2 = cC2; cA3 = cC3;
            rA0 = rC0; rA1 = rC1; rA2 = rC2; rA3 = rC3;
            vA0 = vC0; vA1 = vC1; vA2 = vC2; vA3 = vC3;
            xA0 = xC0; xA1 = xC1; xA2 = xC2; xA3 = xC3;
            cB0 = cD0; cB1 = cD1; cB2 = cD2; cB3 = cD3;
            rB0 = rD0; rB1 = rD1; rB2 = rD2; rB3 = rD3;
            vB0 = vD0; vB1 = vD1; vB2 = vD2; vB3 = vD3;
        }
        FOLD   // final run
#undef CONS
#undef FOLD
#undef LX
#undef LREC
    }

#pragma unroll
    for (int b = 0; b < 8; ++b)
        ZD[(size_t)row * 512 + b * 64 + lane] = pack_bf16(zb[b].x, zb[b].y);
}

// ---------------------------------------------------------------------------
// Dense GEMM (m97-style): out[n, jout] = sum_k Zc[n, k] * Bst[jout, k].
// Block = 128 rows x 128 jout, 256 thr (4 waves, 2x2), K=1024 in 16 BK=64
// slabs. A+B staged via global_load_lds(16B); fragment reads ds_read_b128
// with XOR chunk-swizzle p = row*8 + (kc ^ (row&7)) -> 2-way banks (free).
// ---------------------------------------------------------------------------
__global__ __launch_bounds__(256) void gemm_out_kernel(
        const ushort16* __restrict__ Zc,
        const ushort16* __restrict__ Bst,
        float* __restrict__ out) {
    __shared__ __align__(16) char lds[32768];
    char* Al = lds;               // 16 KB: A slab 128 rows x 64 k
    char* Bl = lds + 16384;       // 16 KB: B slab 128 jout x 64 k

    const int tid  = threadIdx.x;
    const int wave = tid >> 6;
    const int lane = tid & 63;
    const int m    = lane & 15;
    const int half = lane >> 4;
    const int wr   = wave >> 1;          // row half of block
    const int wc   = wave & 1;           // col half of block
    const size_t arow0 = (size_t)blockIdx.x * 128;

    floatx4 acc[16] = {};

    for (int slab = 0; slab < 16; ++slab) {
        const int k0 = slab * 64;
        // stage: physical chunk s holds (row = s>>3, kc = (s&7)^(row&7))
#pragma unroll
        for (int rd = 0; rd < 4; ++rd) {
            int s   = rd * 256 + wave * 64 + lane;
            int row = s >> 3;
            int kc  = (s & 7) ^ (row & 7);
            size_t ldsoff = (size_t)(rd * 256 + wave * 64) * 16;
            gload16(Zc  + ((arow0 + row) << 10) + k0 + (kc << 3), Al + ldsoff);
            gload16(Bst + ((size_t)row << 10)   + k0 + (kc << 3), Bl + ldsoff);
        }
        __syncthreads();

#pragma unroll
        for (int c = 0; c < 2; ++c) {
            short8 a[4], bfr[4];
#pragma unroll
            for (int mt = 0; mt < 4; ++mt) {
                int row = wr * 64 + mt * 16 + m;
                int p   = row * 8 + ((c * 4 + half) ^ (m & 7));
                a[mt] = *(const short8*)(Al + p * 16);
            }
#pragma unroll
            for (int nt = 0; nt < 4; ++nt) {
                int rowb = wc * 64 + nt * 16 + m;
                int p    = rowb * 8 + ((c * 4 + half) ^ (m & 7));
                bfr[nt] = *(const short8*)(Bl + p * 16);
            }
#pragma unroll
            for (int mt = 0; mt < 4; ++mt)
#pragma unroll
                for (int nt = 0; nt < 4; ++nt)
                    acc[mt * 4 + nt] = __builtin_amdgcn_mfma_f32_16x16x32_bf16(
                        a[mt], bfr[nt], acc[mt * 4 + nt], 0, 0, 0);
        }
        __syncthreads();
    }

    // epilogue: C/D layout col = m (jout tile), row = half*4 + reg
#pragma unroll
    for (int mt = 0; mt < 4; ++mt) {
#pragma unroll
        for (int reg = 0; reg < 4; ++reg) {
            int grow = (int)arow0 + wr * 64 + mt * 16 + half * 4 + reg;
            if (grow < NN) {
#pragma unroll
                for (int nt = 0; nt < 4; ++nt)
                    out[(size_t)grow * DOUT + wc * 64 + nt * 16 + m] =
                        acc[mt * 4 + nt][reg];
            }
        }
    }
}

// ---------------------------------------------------------------------------
extern "C" void kernel_launch(void* const* d_in, const int* in_sizes, int n_in,
                              void* d_out, int out_size, void* d_ws, size_t ws_size,
                              hipStream_t stream) {
    const float* X      = (const float*)d_in[0];
    const int*   A_rows = (const int*)d_in[1];
    const int*   A_cols = (const int*)d_in[2];
    const float* A_vals = (const float*)d_in[3];
    const float* basis  = (const float*)d_in[4];
    const float* comp   = (const float*)d_in[5];
    float* out = (float*)d_out;

    // workspace layout (peak ~144.6 MB, under the proven 218.7 MB budget)
    char* ws = (char*)d_ws;
    ushort16* Bst          = (ushort16*)(ws + 0);            // 256 KB
    uint32*   XD           = (uint32*)(ws + 524288);         // 12.8 MB
    int*      ks           = (int*)(ws + 13324288);          // 802816 ints
    uint2*    es           = (uint2*)(ws + 16535552);        // 12.8 MB
    int*      bucket_start = (int*)(ws + 29335552);          // 197 ints
    int*      counts       = (int*)(ws + 29336576);          // 196 ints
    int*      cursor       = (int*)(ws + 29337600);          // 196 ints
    uint2*    es2          = (uint2*)(ws + 29339648);        // 12.8 MB
    ushort16* Zc           = (ushort16*)(ws + 42139648);     // 102.4 MB
    uint32*   ZD           = (uint32*)Zc;

    hipMemsetAsync(counts, 0, NBUCK * sizeof(int), stream);

    build_bst_kernel<<<512, 256, 0, stream>>>(basis, Bst);
    cvt_x_kernel<<<12500, 256, 0, stream>>>(X, XD);

    histB_kernel<<<NBLK_E, 256, 0, stream>>>(A_rows, counts);
    scanB_kernel<<<1, 256, 0, stream>>>(counts, bucket_start, cursor);
    scatterB_kernel<<<NBLK_E, 256, 0, stream>>>(A_rows, A_cols, A_vals,
                                                cursor, es2);
    sortB_kernel<<<NBUCK, 256, 0, stream>>>(es2, bucket_start, es, ks);

    zc_build_kernel<<<12500, 256, 0, stream>>>(es, ks, XD, comp, ZD);

    gemm_out_kernel<<<(NN + 127) / 128, 256, 0, stream>>>(Zc, Bst, out);
}